// Round 11
// baseline (889.440 us; speedup 1.0000x reference)
//
#include <hip/hip_runtime.h>
#include <math.h>

namespace {
constexpr int H = 128, W = 128, NB = 2;
constexpr int HW = H * W;
constexpr int WP = 130, HP = 130, HWP = WP * HP;   // padded image
constexpr int NTHR = 256;
constexpr int DG = 16, CPG = 8, DCN_CIN = 128, DCN_COUT = 64;

// workspace layout (floats). Total = 18,350,080 f = 73,400,320 B (proven size).
constexpr size_t OFF_HA  = 0;
constexpr size_t OFF_HB  = 2163200;
constexpr size_t OFF_PIN = 4326400;
constexpr size_t OFF_O4  = 4194304;
constexpr size_t OFF_XT  = 0;
}

// ---------------------------------------------------------------------------
// Prep: pack ef(192)+flow1(2)+flow2(2) -> padded pin interior, and zero the
// 1-px borders of pin, hA, hB (ws is poisoned each call).
// ---------------------------------------------------------------------------
__global__ __launch_bounds__(NTHR) void prep_k(
    const float* __restrict__ ef, const float* __restrict__ f1,
    const float* __restrict__ f2,
    float* __restrict__ pin, float* __restrict__ hA, float* __restrict__ hB)
{
  constexpr int PACK_N  = NB * 196 * HW;          // 6,422,528
  constexpr int BORD_CH = NB * (196 + 64 + 64);   // 648 channels with borders
  constexpr int BORD_N  = BORD_CH * 516;
  const int total = PACK_N + BORD_N;
  for (int gid = blockIdx.x * NTHR + threadIdx.x; gid < total;
       gid += gridDim.x * NTHR) {
    if (gid < PACK_N) {
      const int b = gid / (196 * HW);
      const int r = gid - b * 196 * HW;
      const int c = r / HW;
      const int p = r - c * HW;
      const int y = p / W, x = p - y * W;
      float v;
      if (c < 192)      v = ef[(b * 192 + c) * HW + p];
      else if (c < 194) v = f1[(b * 2 + (c - 192)) * HW + p];
      else              v = f2[(b * 2 + (c - 194)) * HW + p];
      pin[(size_t)(b * 196 + c) * HWP + (y + 1) * WP + (x + 1)] = v;
    } else {
      const int k  = gid - PACK_N;
      const int ch = k / 516;
      const int e  = k - ch * 516;
      float* base;
      if (ch < NB * 196)            base = pin + (size_t)ch * HWP;
      else if (ch < NB * 196 + NB * 64) base = hA + (size_t)(ch - NB * 196) * HWP;
      else                          base = hB + (size_t)(ch - NB * 196 - NB * 64) * HWP;
      int off;
      if (e < 260) { const int rr = (e < 130) ? 0 : (HP - 1); off = rr * WP + (e % 130); }
      else { const int e2 = e - 260; const int y = 1 + (e2 & 127); off = y * WP + ((e2 < 128) ? 0 : (WP - 1)); }
      base[off] = 0.f;
    }
  }
}

// ---------------------------------------------------------------------------
// 3x3 conv, padded input. 32x32 px tile, each thread a 2x2 pixel patch.
// Software-pipelined staging, 1 barrier/round, double-buffered LDS.
// EPI: 1 = leaky(0.1) -> padded out; 2 = offset/mask activation -> unpadded.
// ---------------------------------------------------------------------------
template<int CIN, int COUT, int CC, int EPI>
__global__ __launch_bounds__(NTHR) void conv3x3_k(
    const float* __restrict__ in,   // padded [NB][CIN][130][130]
    const float* __restrict__ wt,   // [COUT][CIN][9]
    const float* __restrict__ bias,
    const float* __restrict__ fl1, const float* __restrict__ fl2,
    float* __restrict__ out)
{
  constexpr int NST = 2;
  constexpr int HHW = 34, HN = HHW * HHW;          // 34x34 halo = 1156
  constexpr int IN_E = NST * HN;                   // 2312
  constexpr int J_IN = (IN_E + NTHR - 1) / NTHR;   // 10
  constexpr int WT_E = CC * NST * 9;
  constexpr int J_WT = (WT_E + NTHR - 1) / NTHR;
  constexpr int R = CIN / NST;

  __shared__ float s_in[2][NST * HN];
  __shared__ float s_wt[2][CC * NST * 12];

  const int t    = threadIdx.x;
  const int tile = blockIdx.x;                     // 16 tiles (4x4 of 32x32)
  const int tx0  = (tile & 3) * 32, ty0 = (tile >> 2) * 32;
  const int oc0  = blockIdx.y * CC;
  const int b    = blockIdx.z;
  const int px0  = (t & 15) * 2;                   // 2x2 patch base in tile
  const int py0  = (t >> 4) * 2;

  const float* inB = in + (size_t)b * CIN * HWP;

  int iadr[J_IN]; bool ivl[J_IN];
  #pragma unroll
  for (int j = 0; j < J_IN; ++j) {
    const int idx = j * NTHR + t;
    ivl[j] = idx < IN_E;
    const int ii = idx / HN, rem = idx - ii * HN;
    const int hy = rem / HHW, hx = rem - hy * HHW;
    iadr[j] = ivl[j] ? (ii * HWP + (ty0 + hy) * WP + (tx0 + hx)) : 0;
  }
  int wadr[J_WT], wl[J_WT]; bool wvl[J_WT];
  #pragma unroll
  for (int j = 0; j < J_WT; ++j) {
    const int idx = j * NTHR + t;
    wvl[j] = idx < WT_E;
    const int o = idx / (NST * 9), r2 = idx - o * (NST * 9), ii = r2 / 9, k = r2 - ii * 9;
    wadr[j] = wvl[j] ? (((oc0 + o) * CIN + ii) * 9 + k) : 0;
    wl[j]   = wvl[j] ? ((o * NST + ii) * 12 + k) : 0;
  }

  float rin[J_IN], rwt[J_WT], acc[CC][4];
  #pragma unroll
  for (int o = 0; o < CC; ++o)
    #pragma unroll
    for (int p = 0; p < 4; ++p) acc[o][p] = 0.f;

  #pragma unroll
  for (int j = 0; j < J_IN; ++j) if (ivl[j]) rin[j] = inB[iadr[j]];
  #pragma unroll
  for (int j = 0; j < J_WT; ++j) if (wvl[j]) rwt[j] = wt[wadr[j]];

  for (int r = 0; r < R; ++r) {
    float* si = s_in[r & 1];
    float* sw = s_wt[r & 1];
    #pragma unroll
    for (int j = 0; j < J_IN; ++j) if (ivl[j]) si[j * NTHR + t] = rin[j];
    #pragma unroll
    for (int j = 0; j < J_WT; ++j) if (wvl[j]) sw[wl[j]] = rwt[j];
    __syncthreads();
    if (r + 1 < R) {            // prefetch next round, in flight during compute
      const float* ip = inB + (size_t)(r + 1) * NST * HWP;
      const float* wp = wt + (size_t)(r + 1) * NST * 9;
      #pragma unroll
      for (int j = 0; j < J_IN; ++j) if (ivl[j]) rin[j] = ip[iadr[j]];
      #pragma unroll
      for (int j = 0; j < J_WT; ++j) if (wvl[j]) rwt[j] = wp[wadr[j]];
    }
    #pragma unroll
    for (int i = 0; i < NST; ++i) {
      float va[16];
      #pragma unroll
      for (int dy = 0; dy < 4; ++dy)
        #pragma unroll
        for (int dx = 0; dx < 4; ++dx)
          va[dy * 4 + dx] = si[i * HN + (py0 + dy) * HHW + (px0 + dx)];
      #pragma unroll
      for (int o = 0; o < CC; ++o) {
        const float* wr = &sw[(o * NST + i) * 12];
        float w[9];
        #pragma unroll
        for (int k = 0; k < 9; ++k) w[k] = wr[k];
        #pragma unroll
        for (int py = 0; py < 2; ++py)
          #pragma unroll
          for (int px = 0; px < 2; ++px) {
            float a = acc[o][py * 2 + px];
            #pragma unroll
            for (int ky = 0; ky < 3; ++ky)
              #pragma unroll
              for (int kx = 0; kx < 3; ++kx)
                a = fmaf(va[(py + ky) * 4 + (px + kx)], w[ky * 3 + kx], a);
            acc[o][py * 2 + px] = a;
          }
      }
    }
  }

  if (EPI == 2) {
    float flo[2][2][2][2];
    #pragma unroll
    for (int py = 0; py < 2; ++py)
      #pragma unroll
      for (int px = 0; px < 2; ++px) {
        const int pix = (ty0 + py0 + py) * W + (tx0 + px0 + px);
        flo[0][0][py][px] = fl1[(b * 2 + 1) * HW + pix];
        flo[0][1][py][px] = fl1[(b * 2 + 0) * HW + pix];
        flo[1][0][py][px] = fl2[(b * 2 + 1) * HW + pix];
        flo[1][1][py][px] = fl2[(b * 2 + 0) * HW + pix];
      }
    #pragma unroll
    for (int o = 0; o < CC; ++o) {
      const int oc = oc0 + o;
      const float bz = bias[oc];
      const int yx = oc & 1;
      const int sel = ((oc >> 1) / 9 >= 8) ? 1 : 0;
      #pragma unroll
      for (int py = 0; py < 2; ++py)
        #pragma unroll
        for (int px = 0; px < 2; ++px) {
          float rr = acc[o][py * 2 + px] + bz;
          if (oc < 288) rr = 10.f * tanhf(rr) + flo[sel][yx][py][px];
          else          rr = 1.f / (1.f + expf(-rr));
          const int pix = (ty0 + py0 + py) * W + (tx0 + px0 + px);
          out[((size_t)b * COUT + oc) * HW + pix] = rr;
        }
    }
  } else {
    #pragma unroll
    for (int o = 0; o < CC; ++o) {
      const int oc = oc0 + o;
      const float bz = bias[oc];
      #pragma unroll
      for (int py = 0; py < 2; ++py)
        #pragma unroll
        for (int px = 0; px < 2; ++px) {
          float rr = acc[o][py * 2 + px] + bz;
          rr = (rr >= 0.f) ? rr : 0.1f * rr;
          const int y = ty0 + py0 + py, x = tx0 + px0 + px;
          out[((size_t)b * COUT + oc) * HWP + (y + 1) * WP + (x + 1)] = rr;
        }
    }
  }
}

// ---------------------------------------------------------------------------
// Transpose x [B][128][HW] -> x_t [B][16][HW][8] (group-channel interleaved).
// ---------------------------------------------------------------------------
__global__ __launch_bounds__(NTHR) void xpose_k(
    const float* __restrict__ x, float* __restrict__ xt)
{
  constexpr int XT_N = NB * DG * HW;        // 524,288 (b,g,pix) items
  for (int gid = blockIdx.x * NTHR + threadIdx.x; gid < XT_N;
       gid += gridDim.x * NTHR) {
    const int b = gid / (DG * HW);
    const int r = gid - b * DG * HW;
    const int g = r / HW;
    const int p = r - g * HW;
    float4 v0, v1;
    const float* xs = x + ((size_t)(b * DCN_CIN) + g * CPG) * HW + p;
    v0.x = xs[0 * HW]; v0.y = xs[1 * HW]; v0.z = xs[2 * HW]; v0.w = xs[3 * HW];
    v1.x = xs[4 * HW]; v1.y = xs[5 * HW]; v1.z = xs[6 * HW]; v1.w = xs[7 * HW];
    float4* xd = (float4*)(xt + ((size_t)gid) * CPG);
    xd[0] = v0; xd[1] = v1;
  }
}

// ---------------------------------------------------------------------------
// Deform, GEMM-style. Block = 512 thr (8 waves), 64-px tile (8x8), all 16
// groups, all 64 oc (wave w -> oc w*8..w*8+7). Per group: sampling phase
// (thread-parallel: t&63=px, t>>6=k; wave0 also k=8) writes val[px][k*8+c]
// to LDS (stride 76, double-buffered); FMA phase: lane=px reads its 72 vals
// to regs, 576 unrolled FMAs in (c,k)-ascending weight order -> contiguous
// uniform weight loads merge into wide s_loads (round-10: 9216 scattered
// s_load_dword/thread was the stall). No atomics; bias in epilogue.
// ---------------------------------------------------------------------------
__global__ __launch_bounds__(512, 4) void deform_k(
    const float* __restrict__ xt,     // [B][16][HW][8]
    const float* __restrict__ o4,     // [B,432,H,W] activated offset+mask
    const float* __restrict__ dw,     // [64,128,3,3]
    const float* __restrict__ db,
    float* __restrict__ out)          // [B,64,H,W]
{
  constexpr int PXT = 64, VSTR = 76;
  __shared__ float s_val[2][PXT * VSTR];          // 2 x 19,456 B

  const int t    = threadIdx.x;
  const int tile = blockIdx.x;        // 256 tiles (16x16 of 8x8)
  const int b    = blockIdx.y;
  const int tx0  = (tile & 15) * 8, ty0 = (tile >> 4) * 8;
  const int lane = t & 63;            // pixel within tile (all roles)
  const int wv   = t >> 6;            // wave id 0..7
  const int sx   = tx0 + (lane & 7), sy = ty0 + (lane >> 3);
  const int spix = sy * W + sx;

  const float* o4b = o4 + (size_t)b * 432 * HW + spix;
  const float* xtb = xt + (size_t)b * DG * HW * CPG;

  float acc[8];
  #pragma unroll
  for (int o = 0; o < 8; ++o) acc[o] = 0.f;

  // ---- one sample point (g, k) for this thread's pixel -> LDS ----
  auto sample = [&](int g, int k, int buf) {
    const int cb = g * 9 + k;
    const float oy = o4b[(2 * cb + 0) * HW];
    const float ox = o4b[(2 * cb + 1) * HW];
    const float mk = o4b[(288 + cb) * HW];
    const float py  = (float)(sy + k / 3 - 1) + oy;
    const float pxx = (float)(sx + k % 3 - 1) + ox;
    const float y0f = floorf(py), x0f = floorf(pxx);
    const float wy = py - y0f, wx = pxx - x0f;
    const int y0 = (int)y0f, x0 = (int)x0f;
    const bool vy0 = (y0 >= 0) && (y0 < H);
    const bool vy1 = (y0 + 1 >= 0) && (y0 + 1 < H);
    const bool vx0 = (x0 >= 0) && (x0 < W);
    const bool vx1 = (x0 + 1 >= 0) && (x0 + 1 < W);
    const int cy0 = min(max(y0, 0), H - 1);
    const int cy1 = min(max(y0 + 1, 0), H - 1);
    const int cx0 = min(max(x0, 0), W - 1);
    const int cx1 = min(max(x0 + 1, 0), W - 1);
    const float w00 = (vy0 && vx0) ? (1.f - wy) * (1.f - wx) * mk : 0.f;
    const float w01 = (vy0 && vx1) ? (1.f - wy) * wx * mk : 0.f;
    const float w10 = (vy1 && vx0) ? wy * (1.f - wx) * mk : 0.f;
    const float w11 = (vy1 && vx1) ? wy * wx * mk : 0.f;

    const float* xg = xtb + (size_t)g * HW * CPG;
    const float4* p00 = (const float4*)(xg + (size_t)(cy0 * W + cx0) * CPG);
    const float4* p01 = (const float4*)(xg + (size_t)(cy0 * W + cx1) * CPG);
    const float4* p10 = (const float4*)(xg + (size_t)(cy1 * W + cx0) * CPG);
    const float4* p11 = (const float4*)(xg + (size_t)(cy1 * W + cx1) * CPG);
    const float4 a0 = p00[0], a1 = p00[1];
    const float4 b0 = p01[0], b1 = p01[1];
    const float4 c0 = p10[0], c1 = p10[1];
    const float4 d0 = p11[0], d1 = p11[1];

    float4 r0, r1;
    r0.x = fmaf(w00, a0.x, fmaf(w01, b0.x, fmaf(w10, c0.x, w11 * d0.x)));
    r0.y = fmaf(w00, a0.y, fmaf(w01, b0.y, fmaf(w10, c0.y, w11 * d0.y)));
    r0.z = fmaf(w00, a0.z, fmaf(w01, b0.z, fmaf(w10, c0.z, w11 * d0.z)));
    r0.w = fmaf(w00, a0.w, fmaf(w01, b0.w, fmaf(w10, c0.w, w11 * d0.w)));
    r1.x = fmaf(w00, a1.x, fmaf(w01, b1.x, fmaf(w10, c1.x, w11 * d1.x)));
    r1.y = fmaf(w00, a1.y, fmaf(w01, b1.y, fmaf(w10, c1.y, w11 * d1.y)));
    r1.z = fmaf(w00, a1.z, fmaf(w01, b1.z, fmaf(w10, c1.z, w11 * d1.z)));
    r1.w = fmaf(w00, a1.w, fmaf(w10 * 0.f + w01, b1.w, fmaf(w10, c1.w, w11 * d1.w)));
    // (identical formula; written plainly below to avoid typos)
    r1.w = fmaf(w00, a1.w, fmaf(w01, b1.w, fmaf(w10, c1.w, w11 * d1.w)));

    float4* dst = (float4*)&s_val[buf][(lane) * VSTR + k * 8];
    dst[0] = r0; dst[1] = r1;
  };

  auto sample_group = [&](int g, int buf) {
    sample(g, wv, buf);                 // k = 0..7 (one per wave)
    sample(g, wv + 0 == wv ? wv : wv, buf);  // no-op guard (kept simple below)
  };

  // ---- pipeline: sample(0); loop { sample(g+1) ; fma(g) ; barrier } ----
  // sampling for a group = k=wv for all waves, plus k=8 by wave 0
  {
    sample(0, wv, 0);
    if (wv == 0) sample(0, 8, 0);
  }
  __syncthreads();

  for (int g = 0; g < DG; ++g) {
    const int buf = g & 1;
    if (g + 1 < DG) {
      sample(g + 1, wv, buf ^ 1);
      if (wv == 0) sample(g + 1, 8, buf ^ 1);
    }
    // FMA phase: load this lane's 72 vals, then 8 oc x 72 FMAs
    float vv[72];
    {
      const float4* vp = (const float4*)&s_val[buf][lane * VSTR];
      #pragma unroll
      for (int j = 0; j < 18; ++j) {
        const float4 v4 = vp[j];
        vv[j * 4 + 0] = v4.x; vv[j * 4 + 1] = v4.y;
        vv[j * 4 + 2] = v4.z; vv[j * 4 + 3] = v4.w;
      }
    }
    #pragma unroll
    for (int o = 0; o < 8; ++o) {
      const float* wb = dw + ((size_t)(wv * 8 + o) * DCN_CIN + g * CPG) * 9;
      float a = acc[o];
      #pragma unroll
      for (int c = 0; c < CPG; ++c)
        #pragma unroll
        for (int k = 0; k < 9; ++k)
          a = fmaf(vv[k * 8 + c], wb[c * 9 + k], a);
      acc[o] = a;
    }
    __syncthreads();
  }

  float* ob2 = out + ((size_t)b * DCN_COUT + wv * 8) * HW + spix;
  #pragma unroll
  for (int o = 0; o < 8; ++o)
    ob2[(size_t)o * HW] = acc[o] + db[wv * 8 + o];
}

// ---------------------------------------------------------------------------
extern "C" void kernel_launch(void* const* d_in, const int* in_sizes, int n_in,
                              void* d_out, int out_size, void* d_ws, size_t ws_size,
                              hipStream_t stream) {
  const float* x     = (const float*)d_in[0];
  const float* ef    = (const float*)d_in[1];
  const float* fl1   = (const float*)d_in[2];
  const float* fl2   = (const float*)d_in[3];
  const float* w1    = (const float*)d_in[4];
  const float* b1    = (const float*)d_in[5];
  const float* w2    = (const float*)d_in[6];
  const float* b2    = (const float*)d_in[7];
  const float* w3    = (const float*)d_in[8];
  const float* b3    = (const float*)d_in[9];
  const float* w4    = (const float*)d_in[10];
  const float* b4    = (const float*)d_in[11];
  const float* dcn_w = (const float*)d_in[12];
  const float* dcn_b = (const float*)d_in[13];

  float* ws  = (float*)d_ws;
  float* hA  = ws + OFF_HA;
  float* hB  = ws + OFF_HB;
  float* pin = ws + OFF_PIN;
  float* o4  = ws + OFF_O4;
  float* xt  = ws + OFF_XT;     // written after conv4 (hA/hB dead)

  const dim3 blk(NTHR);
  prep_k<<<2048, blk, 0, stream>>>(ef, fl1, fl2, pin, hA, hB);
  // conv1: 196 -> 64, leaky.  32x32 tiles, CC=4 -> 512 blocks
  conv3x3_k<196, 64, 4, 1><<<dim3(16, 16, NB), blk, 0, stream>>>(
      pin, w1, b1, nullptr, nullptr, hA);
  // conv2: 64 -> 64, leaky
  conv3x3_k<64, 64, 4, 1><<<dim3(16, 16, NB), blk, 0, stream>>>(
      hA, w2, b2, nullptr, nullptr, hB);
  // conv3: 64 -> 64, leaky
  conv3x3_k<64, 64, 4, 1><<<dim3(16, 16, NB), blk, 0, stream>>>(
      hB, w3, b3, nullptr, nullptr, hA);
  // conv4: 64 -> 432, fused offset/mask activation.  CC=16 -> 864 blocks
  conv3x3_k<64, 432, 16, 2><<<dim3(16, 27, NB), blk, 0, stream>>>(
      hA, w4, b4, fl1, fl2, o4);
  // transpose x for vectorized gathers
  xpose_k<<<1024, blk, 0, stream>>>(x, xt);
  // deformable conv: 512-thread blocks, 64-px tiles, no atomics
  deform_k<<<dim3(256, NB), dim3(512), 0, stream>>>(xt, o4, dcn_w, dcn_b,
                                                    (float*)d_out);
}